// Round 1
// baseline (399.390 us; speedup 1.0000x reference)
//
#include <hip/hip_runtime.h>
#include <hip/hip_bf16.h>
#include <stdint.h>

// CrossAttention on MI355X (gfx950), bf16 MFMA pipeline.
// Stages: cvt(x)->bf16 | rmsnorm(ctx)->bf16 | transpose weights f32->bf16 |
// q = x@q_w*SCALE | kv = ctxn@kv_w | vT repack | flash attention (clip+softmax,
// no max-tracking needed since logits clipped to +-10) | proj GEMM -> f32 out |
// attn.mean() == 1/K exactly (softmax rows sum to 1).

typedef __bf16 bf16_t;
typedef __bf16 bf16x8 __attribute__((ext_vector_type(8)));
typedef __bf16 bf16x4 __attribute__((ext_vector_type(4)));
typedef float  f32x4  __attribute__((ext_vector_type(4)));

#define BB 4
#define NN 2048
#define KC 2048
#define DD 1024
#define NH 16
#define HD 64

__device__ __forceinline__ f32x4 mfma_16x16x32(bf16x8 a, bf16x8 b, f32x4 c) {
  return __builtin_amdgcn_mfma_f32_16x16x32_bf16(a, b, c, 0, 0, 0);
}

// async global->LDS, 16B per lane; LDS dest is wave-uniform base + lane*16.
__device__ __forceinline__ void gl_lds16(const bf16_t* g, bf16_t* l) {
  __builtin_amdgcn_global_load_lds(
      (const __attribute__((address_space(1))) void*)g,
      (__attribute__((address_space(3))) void*)l, 16, 0, 0);
}

// ---------------- elementwise f32 -> bf16 ----------------
__global__ __launch_bounds__(256) void cvt_f32_bf16(const float* __restrict__ in,
                                                    bf16_t* __restrict__ out, int n4) {
  int i = blockIdx.x * 256 + threadIdx.x;
  if (i >= n4) return;
  float4 v = ((const float4*)in)[i];
  bf16x4 o = {(bf16_t)v.x, (bf16_t)v.y, (bf16_t)v.z, (bf16_t)v.w};
  ((bf16x4*)out)[i] = o;
}

// ---------------- RMSNorm rows of 1024, f32 in -> bf16 out ----------------
__global__ __launch_bounds__(256) void rmsnorm_rows(const float* __restrict__ in,
                                                    bf16_t* __restrict__ out) {
  int row = blockIdx.x, tid = threadIdx.x;
  float4 v = ((const float4*)(in + (size_t)row * DD))[tid];
  float ss = v.x * v.x + v.y * v.y + v.z * v.z + v.w * v.w;
#pragma unroll
  for (int m = 1; m < 64; m <<= 1) ss += __shfl_xor(ss, m);
  __shared__ float wsum[4];
  if ((tid & 63) == 0) wsum[tid >> 6] = ss;
  __syncthreads();
  float total = wsum[0] + wsum[1] + wsum[2] + wsum[3];
  float scale = rsqrtf(total * (1.0f / (float)DD) + 1e-6f);
  bf16x4 o = {(bf16_t)(v.x * scale), (bf16_t)(v.y * scale),
              (bf16_t)(v.z * scale), (bf16_t)(v.w * scale)};
  ((bf16x4*)(out + (size_t)row * DD))[tid] = o;
}

// ---------------- weight transpose: W (R x C) f32 -> WT (C x R) bf16 ----------------
__global__ __launch_bounds__(256) void transpose_w(const float* __restrict__ W,
                                                   bf16_t* __restrict__ WT, int R, int C) {
  __shared__ float tile[32][33];
  int tx = threadIdx.x & 31, ty = threadIdx.x >> 5;
  int r0 = blockIdx.y * 32, c0 = blockIdx.x * 32;
#pragma unroll
  for (int i = 0; i < 4; i++) tile[ty + 8 * i][tx] = W[(size_t)(r0 + ty + 8 * i) * C + c0 + tx];
  __syncthreads();
#pragma unroll
  for (int i = 0; i < 4; i++)
    WT[(size_t)(c0 + ty + 8 * i) * R + r0 + tx] = (bf16_t)tile[tx][ty + 8 * i];
}

// ---------------- GEMM: C(MxN) = (A(MxK) @ Bt(NxK)^T + bias) * alpha ----------------
// m97 structure: 128x128 tile, BK=32, 4 waves in 2x2, 4x4 16x16x32 mfma per wave,
// global_load_lds dwordx4 staging (LDS layout forced: [row][32] contiguous 64B rows).
template <int OUT_F32>
__global__ __launch_bounds__(256, 2) void gemm_bt(const bf16_t* __restrict__ A,
                                                  const bf16_t* __restrict__ Bt,
                                                  const float* __restrict__ bias,
                                                  void* __restrict__ Cout, int M, int N,
                                                  int Kd, float alpha) {
  __shared__ bf16_t As[128 * 32];
  __shared__ bf16_t Bs[128 * 32];
  int tid = threadIdx.x;
  int w = tid >> 6, lane = tid & 63;
  int quad = lane >> 4, l16 = lane & 15;
  int row0 = blockIdx.y * 128, col0 = blockIdx.x * 128;
  int wm = (w >> 1) * 64, wn = (w & 1) * 64;

  f32x4 acc[4][4];
#pragma unroll
  for (int i = 0; i < 4; i++)
#pragma unroll
    for (int j = 0; j < 4; j++) acc[i][j] = (f32x4){0.f, 0.f, 0.f, 0.f};

  for (int kk = 0; kk < Kd; kk += 32) {
#pragma unroll
    for (int call = 0; call < 2; call++) {
      int c = w * 128 + call * 64 + lane;
      gl_lds16(&A[(size_t)(row0 + (c >> 2)) * Kd + kk + (c & 3) * 8],
               &As[(w * 128 + call * 64) * 8]);
      gl_lds16(&Bt[(size_t)(col0 + (c >> 2)) * Kd + kk + (c & 3) * 8],
               &Bs[(w * 128 + call * 64) * 8]);
    }
    __syncthreads();  // drains vmcnt: LDS tiles ready
    bf16x8 af[4], bfr[4];
#pragma unroll
    for (int mi = 0; mi < 4; mi++)
      af[mi] = *(const bf16x8*)&As[(wm + mi * 16 + l16) * 32 + quad * 8];
#pragma unroll
    for (int ni = 0; ni < 4; ni++)
      bfr[ni] = *(const bf16x8*)&Bs[(wn + ni * 16 + l16) * 32 + quad * 8];
#pragma unroll
    for (int mi = 0; mi < 4; mi++)
#pragma unroll
      for (int ni = 0; ni < 4; ni++) acc[mi][ni] = mfma_16x16x32(af[mi], bfr[ni], acc[mi][ni]);
    __syncthreads();  // all reads done before next stage overwrites
  }

#pragma unroll
  for (int ni = 0; ni < 4; ni++) {
    int col = col0 + wn + ni * 16 + l16;
    float bv = bias[col];
#pragma unroll
    for (int mi = 0; mi < 4; mi++) {
#pragma unroll
      for (int r = 0; r < 4; r++) {
        int row = row0 + wm + mi * 16 + quad * 4 + r;  // C/D: row=quad*4+reg, col=lane&15
        float v = (acc[mi][ni][r] + bv) * alpha;
        if (OUT_F32)
          ((float*)Cout)[(size_t)row * N + col] = v;
        else
          ((bf16_t*)Cout)[(size_t)row * N + col] = (bf16_t)v;
      }
    }
  }
}

// ---------------- V repack: kvbuf[b][kc][1024+h*64+hd] -> vT[(b,h)][hd][kc] ----------------
__global__ __launch_bounds__(256) void transpose_v(const bf16_t* __restrict__ kvbuf,
                                                   bf16_t* __restrict__ vT) {
  __shared__ bf16_t tile[64][72];
  int bh = blockIdx.y;
  int b = bh >> 4, h = bh & 15;
  int kc0 = blockIdx.x * 64;
  int tid = threadIdx.x;
#pragma unroll
  for (int i = 0; i < 2; i++) {
    int ch = tid + i * 256;
    int key = ch >> 3, cc = ch & 7;
    *(bf16x8*)&tile[key][cc * 8] =
        *(const bf16x8*)&kvbuf[((size_t)b * KC + kc0 + key) * (2 * DD) + DD + h * HD + cc * 8];
  }
  __syncthreads();
#pragma unroll
  for (int i = 0; i < 2; i++) {
    int ch = tid + i * 256;
    int hd = ch >> 3, cc = ch & 7;
    bf16x8 v;
#pragma unroll
    for (int e = 0; e < 8; e++) v[e] = tile[cc * 8 + e][hd];
    *(bf16x8*)&vT[((size_t)bh * HD + hd) * KC + kc0 + cc * 8] = v;
  }
}

// ---------------- flash attention (no max-tracking: logits clipped to +-10) ----------------
// block = 256 thr (4 waves), q-tile 128 rows, key-tile 64. Each wave owns 32 q-rows.
__global__ __launch_bounds__(256, 2) void flash_attn(const bf16_t* __restrict__ qbuf,
                                                     const bf16_t* __restrict__ kvbuf,
                                                     const bf16_t* __restrict__ vT,
                                                     bf16_t* __restrict__ attn_out) {
  __shared__ bf16_t Qs[128][72];  // +8 pad: quad-lanes land 4 banks apart -> 2-way (free)
  __shared__ bf16_t Ks[64][72];
  __shared__ bf16_t Vs[64][72];   // vT tile: [hd][key]
  __shared__ bf16_t Ps[128][72];
  int tid = threadIdx.x, w = tid >> 6, lane = tid & 63;
  int quad = lane >> 4, l16 = lane & 15;
  int b = blockIdx.y >> 4, h = blockIdx.y & 15;
  int n0 = blockIdx.x * 128;

#pragma unroll
  for (int i = 0; i < 4; i++) {  // load Q tile 128x64
    int ch = tid + i * 256;
    int r = ch >> 3, cc = ch & 7;
    *(bf16x8*)&Qs[r][cc * 8] =
        *(const bf16x8*)&qbuf[((size_t)b * NN + n0 + r) * DD + h * HD + cc * 8];
  }

  f32x4 o[2][4];
  float rs[2][4];
#pragma unroll
  for (int mi = 0; mi < 2; mi++)
#pragma unroll
    for (int ni = 0; ni < 4; ni++) o[mi][ni] = (f32x4){0.f, 0.f, 0.f, 0.f};
#pragma unroll
  for (int mi = 0; mi < 2; mi++)
#pragma unroll
    for (int r = 0; r < 4; r++) rs[mi][r] = 0.f;

  const size_t kvbase = (size_t)b * KC * (2 * DD);
  const size_t vtbase = (size_t)blockIdx.y * HD * KC;

  for (int kc0 = 0; kc0 < KC; kc0 += 64) {
    __syncthreads();  // prev iter's reads of Ks/Vs/Ps done (also covers Q load, iter 0)
#pragma unroll
    for (int i = 0; i < 2; i++) {
      int ch = tid + i * 256;
      int r = ch >> 3, cc = ch & 7;
      *(bf16x8*)&Ks[r][cc * 8] =
          *(const bf16x8*)&kvbuf[kvbase + (size_t)(kc0 + r) * (2 * DD) + h * HD + cc * 8];
      *(bf16x8*)&Vs[r][cc * 8] = *(const bf16x8*)&vT[vtbase + (size_t)r * KC + kc0 + cc * 8];
    }
    __syncthreads();

    // S = Q K^T (per-wave 32x64), then P = exp(clip(S)) -> Ps (C-layout scatter)
#pragma unroll
    for (int mi = 0; mi < 2; mi++) {
      int m = w * 32 + mi * 16 + l16;
      bf16x8 aq0 = *(const bf16x8*)&Qs[m][quad * 8];
      bf16x8 aq1 = *(const bf16x8*)&Qs[m][32 + quad * 8];
#pragma unroll
      for (int ni = 0; ni < 4; ni++) {
        f32x4 s = (f32x4){0.f, 0.f, 0.f, 0.f};
        s = mfma_16x16x32(aq0, *(const bf16x8*)&Ks[ni * 16 + l16][quad * 8], s);
        s = mfma_16x16x32(aq1, *(const bf16x8*)&Ks[ni * 16 + l16][32 + quad * 8], s);
#pragma unroll
        for (int r = 0; r < 4; r++) {
          float sv = fminf(fmaxf(s[r], -10.f), 10.f);
          float p = __expf(sv);
          rs[mi][r] += p;
          Ps[w * 32 + mi * 16 + quad * 4 + r][ni * 16 + l16] = (bf16_t)p;
        }
      }
    }
    // PV: each wave reads only its own 32 Ps rows -> intra-wave dep, no barrier needed
#pragma unroll
    for (int mi = 0; mi < 2; mi++) {
      int m = w * 32 + mi * 16 + l16;
      bf16x8 ap0 = *(const bf16x8*)&Ps[m][quad * 8];
      bf16x8 ap1 = *(const bf16x8*)&Ps[m][32 + quad * 8];
#pragma unroll
      for (int ni = 0; ni < 4; ni++) {
        o[mi][ni] = mfma_16x16x32(ap0, *(const bf16x8*)&Vs[ni * 16 + l16][quad * 8], o[mi][ni]);
        o[mi][ni] =
            mfma_16x16x32(ap1, *(const bf16x8*)&Vs[ni * 16 + l16][32 + quad * 8], o[mi][ni]);
      }
    }
  }

  // row-sum: reduce over the 16 lanes of each quad (same C-layout rows)
#pragma unroll
  for (int mi = 0; mi < 2; mi++)
#pragma unroll
    for (int r = 0; r < 4; r++) {
      float v = rs[mi][r];
      v += __shfl_xor(v, 1);
      v += __shfl_xor(v, 2);
      v += __shfl_xor(v, 4);
      v += __shfl_xor(v, 8);
      rs[mi][r] = v;
    }

#pragma unroll
  for (int mi = 0; mi < 2; mi++)
#pragma unroll
    for (int ni = 0; ni < 4; ni++)
#pragma unroll
      for (int r = 0; r < 4; r++) {
        int row = n0 + w * 32 + mi * 16 + quad * 4 + r;
        int col = h * HD + ni * 16 + l16;
        attn_out[((size_t)b * NN + row) * DD + col] = (bf16_t)(o[mi][ni][r] / rs[mi][r]);
      }
}

__global__ void write_mean(float* out) { out[0] = 1.0f / 2048.0f; }

// ---------------- launch ----------------
extern "C" void kernel_launch(void* const* d_in, const int* in_sizes, int n_in, void* d_out,
                              int out_size, void* d_ws, size_t ws_size, hipStream_t stream) {
  const float* x      = (const float*)d_in[0];
  const float* ctx    = (const float*)d_in[1];
  const float* q_w    = (const float*)d_in[2];
  const float* q_b    = (const float*)d_in[3];
  const float* kv_w   = (const float*)d_in[4];
  const float* kv_b   = (const float*)d_in[5];
  const float* proj_w = (const float*)d_in[6];
  const float* proj_b = (const float*)d_in[7];
  float* out = (float*)d_out;
  char* ws = (char*)d_ws;

  // workspace layout (bytes)
  bf16_t* xb    = (bf16_t*)(ws + 0);          // 16 MB, dead after q GEMM
  bf16_t* ctxn  = (bf16_t*)(ws + 16777216);   // 16 MB, dead after kv GEMM
  bf16_t* qwT   = (bf16_t*)(ws + 33554432);   // 2 MB
  bf16_t* kvwT  = (bf16_t*)(ws + 35651584);   // 4 MB
  bf16_t* pwT   = (bf16_t*)(ws + 39845888);   // 2 MB
  bf16_t* qbuf  = (bf16_t*)(ws + 41943040);   // 16 MB
  bf16_t* kvbuf = (bf16_t*)(ws + 58720256);   // 32 MB
  bf16_t* vT       = ctxn;                    // alias: written after ctxn consumed
  bf16_t* attn_out = xb;                      // alias: written after xb consumed

  cvt_f32_bf16<<<8192, 256, 0, stream>>>(x, xb, (BB * NN * DD) / 4);
  rmsnorm_rows<<<BB * KC, 256, 0, stream>>>(ctx, ctxn);
  transpose_w<<<dim3(32, 32), 256, 0, stream>>>(q_w, qwT, DD, DD);
  transpose_w<<<dim3(64, 32), 256, 0, stream>>>(kv_w, kvwT, DD, 2 * DD);
  transpose_w<<<dim3(32, 32), 256, 0, stream>>>(proj_w, pwT, DD, DD);
  // q = (x @ q_w + q_b) * SCALE  (SCALE=0.125, exact in bf16)
  gemm_bt<0><<<dim3(8, 64), 256, 0, stream>>>(xb, qwT, q_b, qbuf, BB * NN, DD, DD, 0.125f);
  // kv = ctxn @ kv_w + kv_b
  gemm_bt<0><<<dim3(16, 64), 256, 0, stream>>>(ctxn, kvwT, kv_b, kvbuf, BB * KC, 2 * DD, DD, 1.0f);
  transpose_v<<<dim3(KC / 64, BB * NH), 256, 0, stream>>>(kvbuf, vT);
  flash_attn<<<dim3(NN / 128, BB * NH), 256, 0, stream>>>(qbuf, kvbuf, vT, attn_out);
  // out = attn_out @ proj_w + proj_b  (f32 output)
  gemm_bt<1><<<dim3(8, 64), 256, 0, stream>>>(attn_out, pwT, proj_b, out, BB * NN, DD, DD, 1.0f);
  write_mean<<<1, 1, 0, stream>>>(out + (size_t)out_size - 1);
}

// Round 2
// 364.530 us; speedup vs baseline: 1.0956x; 1.0956x over previous
//
#include <hip/hip_runtime.h>
#include <hip/hip_bf16.h>
#include <stdint.h>

// CrossAttention on MI355X (gfx950), bf16 MFMA pipeline.
// R2: flash rebuilt around S^T = K*Q^T so P stays in registers:
//   S^T C-layout (lane&15=query, quad*4+reg=key) IS the A-operand layout of
//   v_mfma_f32_16x16x16bf16_1k -> PV needs no LDS round-trip (R1: 1.7e7 bank
//   conflicts + 32 scalar ds_write_b16/iter eliminated). log2(e) folded into
//   q-GEMM alpha -> softmax = exp2(med3(s,+-14.427)). LDS 54->37KB (4 blk/CU).
//   XCD swizzle: all 16 q-tiles of one (b,h) on one XCD (K/V L2 locality).

typedef __bf16 bf16_t;
typedef __bf16 bf16x8 __attribute__((ext_vector_type(8)));
typedef __bf16 bf16x4 __attribute__((ext_vector_type(4)));
typedef short  s16x4  __attribute__((ext_vector_type(4)));
typedef float  f32x4  __attribute__((ext_vector_type(4)));

#define BB 4
#define NN 2048
#define KC 2048
#define DD 1024
#define NH 16
#define HD 64
// 0.125 (=HEAD_DIM^-0.5) * log2(e): softmax done in exp2 domain
#define QSCALE 0.18033688011112042f
#define CLIP2  14.426950408889634f

__device__ __forceinline__ f32x4 mfma_16x16x32(bf16x8 a, bf16x8 b, f32x4 c) {
  return __builtin_amdgcn_mfma_f32_16x16x32_bf16(a, b, c, 0, 0, 0);
}
__device__ __forceinline__ f32x4 mfma_16x16x16(s16x4 a, s16x4 b, f32x4 c) {
  return __builtin_amdgcn_mfma_f32_16x16x16bf16_1k(a, b, c, 0, 0, 0);
}

// async global->LDS, 16B per lane; LDS dest is wave-uniform base + lane*16.
__device__ __forceinline__ void gl_lds16(const bf16_t* g, bf16_t* l) {
  __builtin_amdgcn_global_load_lds(
      (const __attribute__((address_space(1))) void*)g,
      (__attribute__((address_space(3))) void*)l, 16, 0, 0);
}

// ---------------- elementwise f32 -> bf16 ----------------
__global__ __launch_bounds__(256) void cvt_f32_bf16(const float* __restrict__ in,
                                                    bf16_t* __restrict__ out, int n4) {
  int i = blockIdx.x * 256 + threadIdx.x;
  if (i >= n4) return;
  float4 v = ((const float4*)in)[i];
  bf16x4 o = {(bf16_t)v.x, (bf16_t)v.y, (bf16_t)v.z, (bf16_t)v.w};
  ((bf16x4*)out)[i] = o;
}

// ---------------- RMSNorm rows of 1024, f32 in -> bf16 out ----------------
__global__ __launch_bounds__(256) void rmsnorm_rows(const float* __restrict__ in,
                                                    bf16_t* __restrict__ out) {
  int row = blockIdx.x, tid = threadIdx.x;
  float4 v = ((const float4*)(in + (size_t)row * DD))[tid];
  float ss = v.x * v.x + v.y * v.y + v.z * v.z + v.w * v.w;
#pragma unroll
  for (int m = 1; m < 64; m <<= 1) ss += __shfl_xor(ss, m);
  __shared__ float wsum[4];
  if ((tid & 63) == 0) wsum[tid >> 6] = ss;
  __syncthreads();
  float total = wsum[0] + wsum[1] + wsum[2] + wsum[3];
  float scale = rsqrtf(total * (1.0f / (float)DD) + 1e-6f);
  bf16x4 o = {(bf16_t)(v.x * scale), (bf16_t)(v.y * scale),
              (bf16_t)(v.z * scale), (bf16_t)(v.w * scale)};
  ((bf16x4*)(out + (size_t)row * DD))[tid] = o;
}

// ---------------- weight transpose: W (R x C) f32 -> WT (C x R) bf16 ----------------
__global__ __launch_bounds__(256) void transpose_w(const float* __restrict__ W,
                                                   bf16_t* __restrict__ WT, int R, int C) {
  __shared__ float tile[32][33];
  int tx = threadIdx.x & 31, ty = threadIdx.x >> 5;
  int r0 = blockIdx.y * 32, c0 = blockIdx.x * 32;
#pragma unroll
  for (int i = 0; i < 4; i++) tile[ty + 8 * i][tx] = W[(size_t)(r0 + ty + 8 * i) * C + c0 + tx];
  __syncthreads();
#pragma unroll
  for (int i = 0; i < 4; i++)
    WT[(size_t)(c0 + ty + 8 * i) * R + r0 + tx] = (bf16_t)tile[tx][ty + 8 * i];
}

// ---------------- GEMM: C(MxN) = (A(MxK) @ Bt(NxK)^T + bias) * alpha ----------------
template <int OUT_F32>
__global__ __launch_bounds__(256, 2) void gemm_bt(const bf16_t* __restrict__ A,
                                                  const bf16_t* __restrict__ Bt,
                                                  const float* __restrict__ bias,
                                                  void* __restrict__ Cout, int M, int N,
                                                  int Kd, float alpha) {
  __shared__ bf16_t As[128 * 32];
  __shared__ bf16_t Bs[128 * 32];
  int tid = threadIdx.x;
  int w = tid >> 6, lane = tid & 63;
  int quad = lane >> 4, l16 = lane & 15;
  int row0 = blockIdx.y * 128, col0 = blockIdx.x * 128;
  int wm = (w >> 1) * 64, wn = (w & 1) * 64;

  f32x4 acc[4][4];
#pragma unroll
  for (int i = 0; i < 4; i++)
#pragma unroll
    for (int j = 0; j < 4; j++) acc[i][j] = (f32x4){0.f, 0.f, 0.f, 0.f};

  for (int kk = 0; kk < Kd; kk += 32) {
#pragma unroll
    for (int call = 0; call < 2; call++) {
      int c = w * 128 + call * 64 + lane;
      gl_lds16(&A[(size_t)(row0 + (c >> 2)) * Kd + kk + (c & 3) * 8],
               &As[(w * 128 + call * 64) * 8]);
      gl_lds16(&Bt[(size_t)(col0 + (c >> 2)) * Kd + kk + (c & 3) * 8],
               &Bs[(w * 128 + call * 64) * 8]);
    }
    __syncthreads();
    bf16x8 af[4], bfr[4];
#pragma unroll
    for (int mi = 0; mi < 4; mi++)
      af[mi] = *(const bf16x8*)&As[(wm + mi * 16 + l16) * 32 + quad * 8];
#pragma unroll
    for (int ni = 0; ni < 4; ni++)
      bfr[ni] = *(const bf16x8*)&Bs[(wn + ni * 16 + l16) * 32 + quad * 8];
#pragma unroll
    for (int mi = 0; mi < 4; mi++)
#pragma unroll
      for (int ni = 0; ni < 4; ni++) acc[mi][ni] = mfma_16x16x32(af[mi], bfr[ni], acc[mi][ni]);
    __syncthreads();
  }

#pragma unroll
  for (int ni = 0; ni < 4; ni++) {
    int col = col0 + wn + ni * 16 + l16;
    float bv = bias[col];
#pragma unroll
    for (int mi = 0; mi < 4; mi++) {
#pragma unroll
      for (int r = 0; r < 4; r++) {
        int row = row0 + wm + mi * 16 + quad * 4 + r;
        float v = (acc[mi][ni][r] + bv) * alpha;
        if (OUT_F32)
          ((float*)Cout)[(size_t)row * N + col] = v;
        else
          ((bf16_t*)Cout)[(size_t)row * N + col] = (bf16_t)v;
      }
    }
  }
}

// ---------------- V repack: kvbuf[b][kc][1024+h*64+hd] -> vT[(b,h)][hd][kc] ----------------
__global__ __launch_bounds__(256) void transpose_v(const bf16_t* __restrict__ kvbuf,
                                                   bf16_t* __restrict__ vT) {
  __shared__ bf16_t tile[64][72];
  int bh = blockIdx.y;
  int b = bh >> 4, h = bh & 15;
  int kc0 = blockIdx.x * 64;
  int tid = threadIdx.x;
#pragma unroll
  for (int i = 0; i < 2; i++) {
    int ch = tid + i * 256;
    int key = ch >> 3, cc = ch & 7;
    *(bf16x8*)&tile[key][cc * 8] =
        *(const bf16x8*)&kvbuf[((size_t)b * KC + kc0 + key) * (2 * DD) + DD + h * HD + cc * 8];
  }
  __syncthreads();
#pragma unroll
  for (int i = 0; i < 2; i++) {
    int ch = tid + i * 256;
    int hd = ch >> 3, cc = ch & 7;
    bf16x8 v;
#pragma unroll
    for (int e = 0; e < 8; e++) v[e] = tile[cc * 8 + e][hd];
    *(bf16x8*)&vT[((size_t)bh * HD + hd) * KC + kc0 + cc * 8] = v;
  }
}

// ---------------- flash attention, S^T form, P-in-registers ----------------
// q already scaled by 0.125*log2e; clip in exp2 domain at +-14.427.
// Per block: 128 q-rows, loop over keys in 64-chunks. Wave w owns q-rows
// [w*32, w*32+32). S^T = K*Q^T via 16x16x32 mfma: C-layout lane&15 = query,
// quad*4+reg = key -> registers are directly the A-operand of
// v_mfma_f32_16x16x16bf16_1k for PV (A[m=l16][k=quad*4+j]).
__global__ __launch_bounds__(256, 4) void flash_attn(const bf16_t* __restrict__ qbuf,
                                                     const bf16_t* __restrict__ kvbuf,
                                                     const bf16_t* __restrict__ vT,
                                                     bf16_t* __restrict__ attn_out) {
  __shared__ bf16_t Qs[128][72];
  __shared__ bf16_t Ks[64][72];
  __shared__ bf16_t Vs[64][72];  // [hd][key] tile from vT
  __shared__ __align__(16) float rsh[4][32];
  int tid = threadIdx.x, w = tid >> 6, lane = tid & 63;
  int quad = lane >> 4, l16 = lane & 15;
  // XCD swizzle: blocks land on XCD (bid&7); give each XCD 8 whole (b,h)
  // so K/V for a head are fetched by exactly one XCD's L2.
  int bid = blockIdx.x;          // 0..1023
  int xcd = bid & 7, slot = bid >> 3;
  int bh = xcd * 8 + (slot >> 4);
  int qt = slot & 15;
  int b = bh >> 4, h = bh & 15;
  int n0 = qt * 128;

#pragma unroll
  for (int i = 0; i < 4; i++) {  // load Q tile 128x64
    int ch = tid + i * 256;
    int r = ch >> 3, cc = ch & 7;
    *(bf16x8*)&Qs[r][cc * 8] =
        *(const bf16x8*)&qbuf[((size_t)b * NN + n0 + r) * DD + h * HD + cc * 8];
  }
  __syncthreads();
  // Q fragments (B-operand of S^T) live in registers for the whole K-loop:
  // B[k=d][n=query]: lane = query = w*32 + qi*16 + l16, regs = d (quad*8+j).
  bf16x8 qf[2][2];
#pragma unroll
  for (int qi = 0; qi < 2; qi++)
#pragma unroll
    for (int dc = 0; dc < 2; dc++)
      qf[qi][dc] = *(const bf16x8*)&Qs[w * 32 + qi * 16 + l16][dc * 32 + quad * 8];

  f32x4 o[2][4];
  float rs[2] = {0.f, 0.f};
#pragma unroll
  for (int qi = 0; qi < 2; qi++)
#pragma unroll
    for (int hb = 0; hb < 4; hb++) o[qi][hb] = (f32x4){0.f, 0.f, 0.f, 0.f};

  const size_t kvbase = (size_t)b * KC * (2 * DD) + (size_t)h * HD;
  const size_t vtbase = (size_t)bh * HD * KC;

  for (int kc0 = 0; kc0 < KC; kc0 += 64) {
    __syncthreads();  // prev iter's Ks/Vs reads done
#pragma unroll
    for (int i = 0; i < 2; i++) {
      int ch = tid + i * 256;
      int r = ch >> 3, cc = ch & 7;
      *(bf16x8*)&Ks[r][cc * 8] =
          *(const bf16x8*)&kvbuf[kvbase + (size_t)(kc0 + r) * (2 * DD) + cc * 8];
      *(bf16x8*)&Vs[r][cc * 8] = *(const bf16x8*)&vT[vtbase + (size_t)r * KC + kc0 + cc * 8];
    }
    __syncthreads();

#pragma unroll
    for (int ki = 0; ki < 4; ki++) {
      // A-operand: K[key=ki*16+l16][d]
      bf16x8 kf0 = *(const bf16x8*)&Ks[ki * 16 + l16][quad * 8];
      bf16x8 kf1 = *(const bf16x8*)&Ks[ki * 16 + l16][32 + quad * 8];
      s16x4 pf[2];
#pragma unroll
      for (int qi = 0; qi < 2; qi++) {
        f32x4 s = (f32x4){0.f, 0.f, 0.f, 0.f};
        s = mfma_16x16x32(kf0, qf[qi][0], s);
        s = mfma_16x16x32(kf1, qf[qi][1], s);
        // softmax in exp2 domain; lane's 4 regs = 4 keys of this (ki,quad)
        bf16x4 pb;
#pragma unroll
        for (int r = 0; r < 4; r++) {
          float p = __builtin_amdgcn_exp2f(__builtin_amdgcn_fmed3f(s[r], -CLIP2, CLIP2));
          rs[qi] += p;
          pb[r] = (bf16_t)p;
        }
        pf[qi] = __builtin_bit_cast(s16x4, pb);
      }
      // PV: O[query][hd] += P[query][16 keys of ki] * V[16 keys][hd]
#pragma unroll
      for (int hb = 0; hb < 4; hb++) {
        s16x4 vf = *(const s16x4*)&Vs[hb * 16 + l16][ki * 16 + quad * 4];
#pragma unroll
        for (int qi = 0; qi < 2; qi++) o[qi][hb] = mfma_16x16x16(pf[qi], vf, o[qi][hb]);
      }
    }
  }

  // rs: lane holds partial over its quad's keys; sum across quads (l16 fixed)
#pragma unroll
  for (int qi = 0; qi < 2; qi++) {
    float v = rs[qi];
    v += __shfl_xor(v, 16);
    v += __shfl_xor(v, 32);
    rs[qi] = v;
  }
  if (quad == 0) {
    rsh[w][l16] = 1.0f / rs[0];
    rsh[w][16 + l16] = 1.0f / rs[1];
  }
  __syncthreads();

#pragma unroll
  for (int qi = 0; qi < 2; qi++) {
    f32x4 rv = *(const f32x4*)&rsh[w][qi * 16 + quad * 4];
#pragma unroll
    for (int hb = 0; hb < 4; hb++)
#pragma unroll
      for (int r = 0; r < 4; r++) {
        int row = n0 + w * 32 + qi * 16 + quad * 4 + r;  // C-layout: row=quad*4+reg
        int col = h * HD + hb * 16 + l16;
        attn_out[((size_t)b * NN + row) * DD + col] = (bf16_t)(o[qi][hb][r] * rv[r]);
      }
  }
}

__global__ void write_mean(float* out) { out[0] = 1.0f / 2048.0f; }

// ---------------- launch ----------------
extern "C" void kernel_launch(void* const* d_in, const int* in_sizes, int n_in, void* d_out,
                              int out_size, void* d_ws, size_t ws_size, hipStream_t stream) {
  const float* x      = (const float*)d_in[0];
  const float* ctx    = (const float*)d_in[1];
  const float* q_w    = (const float*)d_in[2];
  const float* q_b    = (const float*)d_in[3];
  const float* kv_w   = (const float*)d_in[4];
  const float* kv_b   = (const float*)d_in[5];
  const float* proj_w = (const float*)d_in[6];
  const float* proj_b = (const float*)d_in[7];
  float* out = (float*)d_out;
  char* ws = (char*)d_ws;

  bf16_t* xb    = (bf16_t*)(ws + 0);          // 16 MB, dead after q GEMM
  bf16_t* ctxn  = (bf16_t*)(ws + 16777216);   // 16 MB, dead after kv GEMM
  bf16_t* qwT   = (bf16_t*)(ws + 33554432);   // 2 MB
  bf16_t* kvwT  = (bf16_t*)(ws + 35651584);   // 4 MB
  bf16_t* pwT   = (bf16_t*)(ws + 39845888);   // 2 MB
  bf16_t* qbuf  = (bf16_t*)(ws + 41943040);   // 16 MB
  bf16_t* kvbuf = (bf16_t*)(ws + 58720256);   // 32 MB
  bf16_t* vT       = ctxn;                    // alias: written after ctxn consumed
  bf16_t* attn_out = xb;                      // alias: written after xb consumed

  cvt_f32_bf16<<<8192, 256, 0, stream>>>(x, xb, (BB * NN * DD) / 4);
  rmsnorm_rows<<<BB * KC, 256, 0, stream>>>(ctx, ctxn);
  transpose_w<<<dim3(32, 32), 256, 0, stream>>>(q_w, qwT, DD, DD);
  transpose_w<<<dim3(64, 32), 256, 0, stream>>>(kv_w, kvwT, DD, 2 * DD);
  transpose_w<<<dim3(32, 32), 256, 0, stream>>>(proj_w, pwT, DD, DD);
  // q = (x @ q_w + q_b) * (SCALE*log2e)  -> softmax uses exp2
  gemm_bt<0><<<dim3(8, 64), 256, 0, stream>>>(xb, qwT, q_b, qbuf, BB * NN, DD, DD, QSCALE);
  gemm_bt<0><<<dim3(16, 64), 256, 0, stream>>>(ctxn, kvwT, kv_b, kvbuf, BB * KC, 2 * DD, DD, 1.0f);
  transpose_v<<<dim3(KC / 64, BB * NH), 256, 0, stream>>>(kvbuf, vT);
  flash_attn<<<1024, 256, 0, stream>>>(qbuf, kvbuf, vT, attn_out);
  gemm_bt<1><<<dim3(8, 64), 256, 0, stream>>>(attn_out, pwT, proj_b, out, BB * NN, DD, DD, 1.0f);
  write_mean<<<1, 1, 0, stream>>>(out + (size_t)out_size - 1);
}